// Round 8
// baseline (176.459 us; speedup 1.0000x reference)
//
#include <hip/hip_runtime.h>

#define HH 128
#define WW 128
#define CIN 256
#define COUT 256
#define KTOT 2304   // 9 * 256, k = kk*256 + ci
#define HW (HH * WW)
#define NIT 36      // 9 taps * 4 channel-chunks of 64

typedef __attribute__((ext_vector_type(8))) short short8;
typedef __attribute__((ext_vector_type(4))) float f32x4;
typedef __attribute__((ext_vector_type(2))) float f32x2;

__device__ __forceinline__ unsigned rne_bf16(float f) {
  unsigned u = __float_as_uint(f);
  return (u + 0x7FFFu + ((u >> 16) & 1u)) >> 16;
}
__device__ __forceinline__ unsigned cvt_pk_bf16(float lo, float hi) {
  unsigned r;
  asm("v_cvt_pk_bf16_f32 %0, %1, %2" : "=v"(r) : "v"(lo), "v"(hi));
  return r;
}
// unpack bf16x2 word -> {lo,hi} as exact f32 pair
__device__ __forceinline__ f32x2 up2(unsigned u) {
  f32x2 r;
  r.x = __uint_as_float(u << 16);
  r.y = __uint_as_float(u & 0xFFFF0000u);
  return r;
}
__device__ __forceinline__ f32x2 pkmul(f32x2 w, f32x2 v) {
  f32x2 d;
  asm("v_pk_mul_f32 %0, %1, %2" : "=v"(d) : "v"(w), "v"(v));
  return d;
}
__device__ __forceinline__ f32x2 pkfma(f32x2 w, f32x2 v, f32x2 c) {
  f32x2 d;
  asm("v_pk_fma_f32 %0, %1, %2, %3" : "=v"(d) : "v"(w), "v"(v), "v"(c));
  return d;
}

__device__ __forceinline__ void glds16(const void* g, void* l) {
  __builtin_amdgcn_global_load_lds(
      (const __attribute__((address_space(1))) void*)g,
      (__attribute__((address_space(3))) void*)l, 16, 0, 0);
}

// prep (vectorized):
//  blocks [0,2048):    transpose x [N][CIN][H][W] fp32 -> xt [N][H][W][CIN] bf16
//  blocks [2048,3200): weight [COUT][CIN][3][3] fp32 -> wT [COUT][kk*256+ci] bf16
__global__ void prep_inputs(const float* __restrict__ x, const float* __restrict__ wsrc,
                            unsigned short* __restrict__ xt, unsigned short* __restrict__ wT) {
  int b = blockIdx.x;
  __shared__ __align__(16) float tile[64][68];  // [w][ci], 17.4 KB
  int tid = threadIdx.x;
  if (b < 2048) {
    int wg = b & 1, cg = (b >> 1) & 3, nh = b >> 3;
    int n = nh >> 7, h = nh & 127;
    const float* xp = x + (((size_t)n * CIN + cg * 64) * HH + h) * WW + wg * 64;
#pragma unroll
    for (int r = 0; r < 4; ++r) {
      int e = r * 256 + tid;            // 0..1023
      int ci = e >> 4, w4 = (e & 15) * 4;
      float4 v = *(const float4*)(xp + (size_t)ci * HW + w4);
      tile[w4 + 0][ci] = v.x;
      tile[w4 + 1][ci] = v.y;
      tile[w4 + 2][ci] = v.z;
      tile[w4 + 3][ci] = v.w;
    }
    __syncthreads();
    unsigned short* dst = xt + (((size_t)(n * HH + h) * WW) + wg * 64) * CIN + cg * 64;
#pragma unroll
    for (int r = 0; r < 2; ++r) {
      int e = r * 256 + tid;            // 0..511
      int w = e >> 3, c8 = (e & 7) * 8;
      const float* tp = &tile[w][c8];
      f32x4 lo = *(const f32x4*)tp;
      f32x4 hi = *(const f32x4*)(tp + 4);
      uint4 o;
      o.x = cvt_pk_bf16(lo.x, lo.y);
      o.y = cvt_pk_bf16(lo.z, lo.w);
      o.z = cvt_pk_bf16(hi.x, hi.y);
      o.w = cvt_pk_bf16(hi.z, hi.w);
      *(uint4*)(dst + (size_t)w * CIN + c8) = o;
    }
  } else {
    int o = (b - 2048) * 512 + tid * 2;
    if (o >= COUT * KTOT) return;
    int co = o / KTOT;
    int r = o - co * KTOT;              // even; r == k == kk*256 + ci
    int kk = r >> 8, ci = r & 255;
    float v0 = wsrc[(size_t)(co * CIN + ci) * 9 + kk];
    float v1 = wsrc[(size_t)(co * CIN + ci + 1) * 9 + kk];
    *(unsigned*)(wT + o) = cvt_pk_bf16(v0, v1);
  }
}

// R12: producer/consumer wave specialization. R11's counters showed VALU 42%
// + LDS ~58% SUMMING (lockstep phases) -> split the pipes across waves:
//   waves 0-3 (consumers): 64x64 tiles, acc[4][4]; 16 ds_read + 32 MFMA/iter;
//     no VALU blend, no vm-ops. Square tiles cut block LDS-read 96->64KB/iter.
//   waves 4-7 (producers): all gathers + blend + A ds_write + B glds + prep.
// One barrier/iter; producers wait vmcnt(8) (drain glds, gathers fly),
// consumers wait lgkm(0) only. setprio(1) on consumer MFMA (real role-split).
__global__ __launch_bounds__(512, 2) void fused_deform_gemm(
    const float* __restrict__ obb, const unsigned short* __restrict__ xt,
    const unsigned short* __restrict__ wT, float* __restrict__ out,
    const int* __restrict__ stride_p) {
  int g = blockIdx.x;
  int xcd = g & 7, li = g >> 3;
  int u = xcd * 64 + li;   // 0..511; each XCD gets a contiguous 32-row band
  int mh = u & 1;          // which half of the image row
  int bm = u >> 1;         // row id 0..255
  int n = bm >> 7, h = bm & 127;
  int tid = threadIdx.x;

  // 128B rows, phys byte = row*128 + (colbyte ^ ((row&7)<<4)); both dbuf
  __shared__ __align__(16) unsigned short Alds[2][64 * 64];    // 16 KB
  __shared__ __align__(16) unsigned short Blds[2][256 * 64];   // 64 KB

  int lane = tid & 63;
  int wv = tid >> 6;          // 0..7
  bool isProd = (wv >= 4);
  int l15 = lane & 15, l4 = lane >> 4;

  char* AB = (char*)&Alds[0][0];
  char* BB = (char*)&Blds[0][0];

  // ---------------- consumer setup (waves 0..3) ----------------
  int wn = wv * 64;           // cout base; wave tile 64px x 64co
  int rdXor = (l15 & 7) << 4;
  int rc0 = (l4 * 16) ^ rdXor;        // ks = 0
  int rc1 = (64 + l4 * 16) ^ rdXor;   // ks = 32
  f32x4 acc[4][4] = {};

  // ---------------- producer setup (waves 4..7) ----------------
  int pv = wv - 4;                 // 0..3
  int pt = tid & 255;              // producer-local id
  int p = pt >> 2;                 // pixel 0..63 (4 threads per pixel)
  int chunk4 = pt & 3;             // 16-channel chunk within the 64-ch slice
  int AldsOff0 = p * 128 + ((chunk4 * 32) ^ ((p & 7) << 4));
  int AldsOff1 = p * 128 + ((chunk4 * 32 + 16) ^ ((p & 7) << 4));
  // B glds: 8 ops/wave; lane -> row t*32 + pv*8 + (lane>>3), phys col (lane&7)*16
  int cbl = ((lane & 7) * 16) ^ (((lane >> 3) & 7) << 4);
  const char* wTb = (const char*)wT + (pv * 8 + (lane >> 3)) * (KTOT * 2) + cbl;

  float cx_, cy_, pa_, pb_, pc_, pd_;
  if (isProd) {
    float inv_s = 1.0f / (float)stride_p[0];
    int w = mh * 64 + p;
    const float* op = obb + ((size_t)n * 5 * HH + h) * WW + w;
    float xc = op[0] * inv_s;
    float yc = op[(size_t)1 * HW] * inv_s;
    float bw = op[(size_t)2 * HW] * inv_s;
    float bh = op[(size_t)3 * HW] * inv_s;
    float th = op[(size_t)4 * HW];
    float sn, cs;
    sincosf(th, &sn, &cs);
    float dw = bw * (1.0f / 3.0f), dh = bh * (1.0f / 3.0f);
    cx_ = xc; cy_ = yc;
    pa_ = dw * cs; pb_ = dh * sn;
    pc_ = dw * sn; pd_ = dh * cs;
  }

  f32x2 wgt2[4];   // bilinear weights (duplicated pairs)
  int boff[4];     // corner base element offsets
  uint4 pf0[4], pf1[4];  // prefetched corners (half 0: ch+0..7, half 1: +8..15)
  uint4 aw0, aw1;  // blended A chunks

  auto prep = [&](int kk) {
    float fky = (float)(kk / 3 - 1);
    float fkx = (float)(kk % 3 - 1);
    float sx = cx_ + fkx * pa_ - fky * pb_;
    float sy = cy_ + fkx * pc_ + fky * pd_;
    float fx = floorf(sx), fy = floorf(sy);
    float lx = sx - fx, ly = sy - fy;
    int x0 = (int)fx, y0 = (int)fy;
    float vy0 = (y0 >= 0 && y0 < HH) ? 1.0f : 0.0f;
    float vy1 = (y0 >= -1 && y0 < HH - 1) ? 1.0f : 0.0f;
    float vx0 = (x0 >= 0 && x0 < WW) ? 1.0f : 0.0f;
    float vx1 = (x0 >= -1 && x0 < WW - 1) ? 1.0f : 0.0f;
    float w00 = (1.0f - ly) * (1.0f - lx) * vy0 * vx0;
    float w01 = (1.0f - ly) * lx * vy0 * vx1;
    float w10 = ly * (1.0f - lx) * vy1 * vx0;
    float w11 = ly * lx * vy1 * vx1;
    wgt2[0] = (f32x2){w00, w00};
    wgt2[1] = (f32x2){w01, w01};
    wgt2[2] = (f32x2){w10, w10};
    wgt2[3] = (f32x2){w11, w11};
    int xc0 = min(max(x0, 0), WW - 1), xc1 = min(max(x0 + 1, 0), WW - 1);
    int yc0 = min(max(y0, 0), HH - 1), yc1 = min(max(y0 + 1, 0), HH - 1);
    int rb0 = (n * HH + yc0) * WW, rb1 = (n * HH + yc1) * WW;
    boff[0] = (rb0 + xc0) * CIN;
    boff[1] = (rb0 + xc1) * CIN;
    boff[2] = (rb1 + xc0) * CIN;
    boff[3] = (rb1 + xc1) * CIN;
  };

  auto issueA = [&](int cc) {
    int co = cc * 64 + chunk4 * 16;
#pragma unroll
    for (int c = 0; c < 4; ++c) {
      pf0[c] = *(const uint4*)(xt + boff[c] + co);
      pf1[c] = *(const uint4*)(xt + boff[c] + co + 8);
    }
  };

  auto blendW = [&](unsigned a, unsigned b, unsigned c, unsigned d) -> unsigned {
    f32x2 s = pkmul(wgt2[0], up2(a));
    s = pkfma(wgt2[1], up2(b), s);
    s = pkfma(wgt2[2], up2(c), s);
    s = pkfma(wgt2[3], up2(d), s);
    return cvt_pk_bf16(s.x, s.y);
  };

  auto blendA = [&]() {
    uint4 r;
    r.x = blendW(pf0[0].x, pf0[1].x, pf0[2].x, pf0[3].x);
    r.y = blendW(pf0[0].y, pf0[1].y, pf0[2].y, pf0[3].y);
    r.z = blendW(pf0[0].z, pf0[1].z, pf0[2].z, pf0[3].z);
    r.w = blendW(pf0[0].w, pf0[1].w, pf0[2].w, pf0[3].w);
    aw0 = r;
    r.x = blendW(pf1[0].x, pf1[1].x, pf1[2].x, pf1[3].x);
    r.y = blendW(pf1[0].y, pf1[1].y, pf1[2].y, pf1[3].y);
    r.z = blendW(pf1[0].z, pf1[1].z, pf1[2].z, pf1[3].z);
    r.w = blendW(pf1[0].w, pf1[1].w, pf1[2].w, pf1[3].w);
    aw1 = r;
  };

  auto stageB = [&](int itn, int nbuf) {
    const char* src = wTb + itn * 128;
    char* Bd = BB + nbuf * 32768;
#pragma unroll
    for (int t = 0; t < 8; ++t)
      glds16(src + t * (32 * KTOT * 2), Bd + (t * 32 + pv * 8) * 128);
  };

  // ---- prologue: producers stage tile 0 into buf0; gathers(1) in flight ----
  if (isProd) {
    prep(0);
    issueA(0);
    blendA();
    *(uint4*)(AB + AldsOff0) = aw0;
    *(uint4*)(AB + AldsOff1) = aw1;
    stageB(0, 0);
    issueA(1);   // newest 8 vm-ops
    asm volatile("s_waitcnt vmcnt(8) lgkmcnt(0)" ::: "memory");
  }
  __builtin_amdgcn_s_barrier();
  asm volatile("" ::: "memory");

  for (int it = 0; it < NIT; ++it) {
    int buf = it & 1, nbuf = buf ^ 1;

    if (isProd) {
      // ---- produce tile it+1 into nbuf; gathers for it+2 issued last ----
      if (it + 1 < NIT) {
        stageB(it + 1, nbuf);              // glds first: L2 latency hides
        blendA();                          // consumes pf (gathers it+1)
        *(uint4*)(AB + nbuf * 8192 + AldsOff0) = aw0;
        *(uint4*)(AB + nbuf * 8192 + AldsOff1) = aw1;
        int t2 = it + 2;
        if (t2 < NIT) {
          if ((t2 & 3) == 0) prep(t2 >> 2);
          issueA(t2 & 3);
          asm volatile("s_waitcnt vmcnt(8) lgkmcnt(0)" ::: "memory");
        } else {
          asm volatile("s_waitcnt vmcnt(0) lgkmcnt(0)" ::: "memory");
        }
      }
    } else {
      // ---- consume buf: 64x64 tile, A+B from LDS (swizzled, conflict-free) ----
      char* ABr = AB + buf * 8192;
      char* BBr = BB + buf * 32768;
      __builtin_amdgcn_s_setprio(1);
#pragma unroll
      for (int ksi = 0; ksi < 2; ++ksi) {
        int rc = ksi ? rc1 : rc0;
        short8 af[4];
#pragma unroll
        for (int i = 0; i < 4; ++i)
          af[i] = *(const short8*)(ABr + (i * 16 + l15) * 128 + rc);
#pragma unroll
        for (int j = 0; j < 4; ++j) {
          short8 bf = *(const short8*)(BBr + (wn + j * 16 + l15) * 128 + rc);
#pragma unroll
          for (int i = 0; i < 4; ++i)
            acc[i][j] = __builtin_amdgcn_mfma_f32_16x16x32_bf16(af[i], bf, acc[i][j], 0, 0, 0);
        }
      }
      __builtin_amdgcn_s_setprio(0);
      asm volatile("s_waitcnt lgkmcnt(0)" ::: "memory");
    }

    if (it + 1 < NIT) {
      __builtin_amdgcn_s_barrier();
      asm volatile("" ::: "memory");
    }
  }

  // ---- epilogue (consumers only): out[n][co][h][w], float4 along w ----
  if (!isProd) {
    float* outp = out + (size_t)n * COUT * HW + (size_t)h * WW + mh * 64;
#pragma unroll
    for (int i = 0; i < 4; ++i) {
      int w0 = i * 16 + l4 * 4;
#pragma unroll
      for (int j = 0; j < 4; ++j) {
        int co = wn + j * 16 + l15;
        *(f32x4*)(outp + (size_t)co * HW + w0) = acc[i][j];
      }
    }
  }
}

extern "C" void kernel_launch(void* const* d_in, const int* in_sizes, int n_in,
                              void* d_out, int out_size, void* d_ws, size_t ws_size,
                              hipStream_t stream) {
  const float* x = (const float*)d_in[0];
  const float* obb = (const float*)d_in[1];
  const float* wgt = (const float*)d_in[2];
  const int* stridep = (const int*)d_in[3];
  float* out = (float*)d_out;

  unsigned short* xt = (unsigned short*)d_ws;          // 2*128*128*256 bf16 = 16.8 MB
  unsigned short* wT = xt + (size_t)2 * HH * WW * CIN; // 256*2304 bf16 = 1.2 MB

  prep_inputs<<<dim3(2048 + 1152), 256, 0, stream>>>(x, wgt, xt, wT);
  fused_deform_gemm<<<dim3(512), 512, 0, stream>>>(obb, xt, wT, out, stridep);
}

// Round 12
// 159.244 us; speedup vs baseline: 1.1081x; 1.1081x over previous
//
#include <hip/hip_runtime.h>

#define HH 128
#define WW 128
#define CIN 256
#define COUT 256
#define KTOT 2304   // 9 * 256, k = kk*256 + ci
#define HW (HH * WW)
#define NIT 36      // 9 taps * 4 channel-chunks of 64

typedef __attribute__((ext_vector_type(8))) short short8;
typedef __attribute__((ext_vector_type(4))) float f32x4;
typedef __attribute__((ext_vector_type(2))) float f32x2;

__device__ __forceinline__ unsigned rne_bf16(float f) {
  unsigned u = __float_as_uint(f);
  return (u + 0x7FFFu + ((u >> 16) & 1u)) >> 16;
}
__device__ __forceinline__ unsigned cvt_pk_bf16(float lo, float hi) {
  unsigned r;
  asm("v_cvt_pk_bf16_f32 %0, %1, %2" : "=v"(r) : "v"(lo), "v"(hi));
  return r;
}
// unpack bf16x2 word -> {lo,hi} as exact f32 pair
__device__ __forceinline__ f32x2 up2(unsigned u) {
  f32x2 r;
  r.x = __uint_as_float(u << 16);
  r.y = __uint_as_float(u & 0xFFFF0000u);
  return r;
}
__device__ __forceinline__ f32x2 pkmul(f32x2 w, f32x2 v) {
  f32x2 d;
  asm("v_pk_mul_f32 %0, %1, %2" : "=v"(d) : "v"(w), "v"(v));
  return d;
}
__device__ __forceinline__ f32x2 pkfma(f32x2 w, f32x2 v, f32x2 c) {
  f32x2 d;
  asm("v_pk_fma_f32 %0, %1, %2, %3" : "=v"(d) : "v"(w), "v"(v), "v"(c));
  return d;
}

__device__ __forceinline__ void glds16(const void* g, void* l) {
  __builtin_amdgcn_global_load_lds(
      (const __attribute__((address_space(1))) void*)g,
      (__attribute__((address_space(3))) void*)l, 16, 0, 0);
}

// prep (vectorized, unchanged & verified):
//  blocks [0,2048):    transpose x [N][CIN][H][W] fp32 -> xt [N][H][W][CIN] bf16
//  blocks [2048,3200): weight [COUT][CIN][3][3] fp32 -> wT [COUT][kk*256+ci] bf16
__global__ void prep_inputs(const float* __restrict__ x, const float* __restrict__ wsrc,
                            unsigned short* __restrict__ xt, unsigned short* __restrict__ wT) {
  int b = blockIdx.x;
  __shared__ __align__(16) float tile[64][68];  // [w][ci], 17.4 KB
  int tid = threadIdx.x;
  if (b < 2048) {
    int wg = b & 1, cg = (b >> 1) & 3, nh = b >> 3;
    int n = nh >> 7, h = nh & 127;
    const float* xp = x + (((size_t)n * CIN + cg * 64) * HH + h) * WW + wg * 64;
#pragma unroll
    for (int r = 0; r < 4; ++r) {
      int e = r * 256 + tid;            // 0..1023
      int ci = e >> 4, w4 = (e & 15) * 4;
      float4 v = *(const float4*)(xp + (size_t)ci * HW + w4);
      tile[w4 + 0][ci] = v.x;
      tile[w4 + 1][ci] = v.y;
      tile[w4 + 2][ci] = v.z;
      tile[w4 + 3][ci] = v.w;
    }
    __syncthreads();
    unsigned short* dst = xt + (((size_t)(n * HH + h) * WW) + wg * 64) * CIN + cg * 64;
#pragma unroll
    for (int r = 0; r < 2; ++r) {
      int e = r * 256 + tid;            // 0..511
      int w = e >> 3, c8 = (e & 7) * 8;
      const float* tp = &tile[w][c8];
      f32x4 lo = *(const f32x4*)tp;
      f32x4 hi = *(const f32x4*)(tp + 4);
      uint4 o;
      o.x = cvt_pk_bf16(lo.x, lo.y);
      o.y = cvt_pk_bf16(lo.z, lo.w);
      o.z = cvt_pk_bf16(hi.x, hi.y);
      o.w = cvt_pk_bf16(hi.z, hi.w);
      *(uint4*)(dst + (size_t)w * CIN + c8) = o;
    }
  } else {
    int o = (b - 2048) * 512 + tid * 2;
    if (o >= COUT * KTOT) return;
    int co = o / KTOT;
    int r = o - co * KTOT;              // even; r == k == kk*256 + ci
    int kk = r >> 8, ci = r & 255;
    float v0 = wsrc[(size_t)(co * CIN + ci) * 9 + kk];
    float v1 = wsrc[(size_t)(co * CIN + ci + 1) * 9 + kk];
    *(unsigned*)(wT + o) = cvt_pk_bf16(v0, v1);
  }
}

// R15: back to the VERIFIED R6 structure (single-buf A+B, two barriers/iter,
// glds-B, vmcnt(0) at the stage barrier) with ONE delta: obb params computed
// PER-THREAD (R11-verified code) instead of LDS arrays. LDS drops 42496 ->
// 40960 B = EXACTLY 4 blocks/CU (163840 = 160KB): 32 waves/CU, up from 24.
// Rationale: R6 (3 blocks/CU) beat every fancier schedule; cross-block phase
// interleave (m114) is what overlaps blend-VALU with LDS/MFMA. (512,4) caps
// VGPR at 64 (R11 measured 56 with identical register set -> no spill).
__global__ __launch_bounds__(512, 4) void fused_deform_gemm(
    const float* __restrict__ obb, const unsigned short* __restrict__ xt,
    const unsigned short* __restrict__ wT, float* __restrict__ out,
    const int* __restrict__ stride_p) {
  int g = blockIdx.x;
  int xcd = g & 7, li = g >> 3;
  int u = xcd * 64 + li;   // 0..511; each XCD gets a contiguous 32-row band
  int mh = u & 1;          // which half of the image row
  int bm = u >> 1;         // row id 0..255
  int n = bm >> 7, h = bm & 127;
  int tid = threadIdx.x;

  // 128B rows, phys byte = row*128 + (colbyte ^ ((row&7)<<4)); single buffers
  __shared__ __align__(16) unsigned short Alds[64 * 64];    // 8 KB
  __shared__ __align__(16) unsigned short Blds[256 * 64];   // 32 KB

  int lane = tid & 63;
  int wv = tid >> 6;          // 0..7
  int wm = (wv & 1) * 32;     // wave pixel base (32px x 64co wave tile)
  int wn = (wv >> 1) * 64;    // wave cout base
  int l15 = lane & 15, l4 = lane >> 4;

  // A-build: 8 lanes per pixel, one 16B (8-channel) chunk per thread.
  int chunk8 = (lane & 7) * 8;
  int p = wv * 8 + (lane >> 3);    // this thread's pixel, 0..63
  int AldsOff = p * 128 + (((lane & 7) * 16) ^ ((p & 7) << 4));

  // B staging via glds: 4 wave-ops/iter; lane -> row t*64 + wv*8 + (lane>>3),
  // phys col (lane&7)*16; source pre-swizzled (involution == read XOR).
  int cbl = ((lane & 7) * 16) ^ (((lane >> 3) & 7) << 4);
  const char* wTb = (const char*)wT + (wv * 8 + (lane >> 3)) * (KTOT * 2) + cbl;
  int BldsC[4];   // wave-uniform LDS byte offsets
#pragma unroll
  for (int t = 0; t < 4; ++t) BldsC[t] = (t * 64 + wv * 8) * 128;

  // per-thread obb params for pixel p (replaces R6's 1.5KB LDS param arrays)
  float cx_, cy_, pa_, pb_, pc_, pd_;
  {
    float inv_s = 1.0f / (float)stride_p[0];
    int w = mh * 64 + p;
    const float* op = obb + ((size_t)n * 5 * HH + h) * WW + w;
    float xc = op[0] * inv_s;
    float yc = op[(size_t)1 * HW] * inv_s;
    float bw = op[(size_t)2 * HW] * inv_s;
    float bh = op[(size_t)3 * HW] * inv_s;
    float th = op[(size_t)4 * HW];
    float sn, cs;
    sincosf(th, &sn, &cs);
    float dw = bw * (1.0f / 3.0f), dh = bh * (1.0f / 3.0f);
    cx_ = xc; cy_ = yc;
    pa_ = dw * cs; pb_ = dh * sn;
    pc_ = dw * sn; pd_ = dh * cs;
  }

  f32x4 acc[2][4] = {};

  // fragment-read column byte offsets (frag row &7 == l15&7)
  int rdXor = (l15 & 7) << 4;
  int rc0 = (l4 * 16) ^ rdXor;        // ks = 0
  int rc1 = (64 + l4 * 16) ^ rdXor;   // ks = 32

  f32x2 wgt2[4];  // bilinear weights (duplicated pairs)
  int boff[4];    // corner base element offsets
  uint4 pf[4];    // prefetched corner data
  uint4 aw;       // blended A chunk awaiting staging

  auto prep = [&](int kk) {
    float fky = (float)(kk / 3 - 1);
    float fkx = (float)(kk % 3 - 1);
    float sx = cx_ + fkx * pa_ - fky * pb_;
    float sy = cy_ + fkx * pc_ + fky * pd_;
    float fx = floorf(sx), fy = floorf(sy);
    float lx = sx - fx, ly = sy - fy;
    int x0 = (int)fx, y0 = (int)fy;
    float vy0 = (y0 >= 0 && y0 < HH) ? 1.0f : 0.0f;
    float vy1 = (y0 >= -1 && y0 < HH - 1) ? 1.0f : 0.0f;
    float vx0 = (x0 >= 0 && x0 < WW) ? 1.0f : 0.0f;
    float vx1 = (x0 >= -1 && x0 < WW - 1) ? 1.0f : 0.0f;
    float w00 = (1.0f - ly) * (1.0f - lx) * vy0 * vx0;
    float w01 = (1.0f - ly) * lx * vy0 * vx1;
    float w10 = ly * (1.0f - lx) * vy1 * vx0;
    float w11 = ly * lx * vy1 * vx1;
    wgt2[0] = (f32x2){w00, w00};
    wgt2[1] = (f32x2){w01, w01};
    wgt2[2] = (f32x2){w10, w10};
    wgt2[3] = (f32x2){w11, w11};
    int xc0 = min(max(x0, 0), WW - 1), xc1 = min(max(x0 + 1, 0), WW - 1);
    int yc0 = min(max(y0, 0), HH - 1), yc1 = min(max(y0 + 1, 0), HH - 1);
    int rb0 = (n * HH + yc0) * WW, rb1 = (n * HH + yc1) * WW;
    boff[0] = (rb0 + xc0) * CIN;
    boff[1] = (rb0 + xc1) * CIN;
    boff[2] = (rb1 + xc0) * CIN;
    boff[3] = (rb1 + xc1) * CIN;
  };

  auto issueA = [&](int cc) {
    int co = cc * 64 + chunk8;
#pragma unroll
    for (int c = 0; c < 4; ++c)
      pf[c] = *(const uint4*)(xt + boff[c] + co);
  };

  auto blendW = [&](unsigned a, unsigned b, unsigned c, unsigned d) -> unsigned {
    f32x2 s = pkmul(wgt2[0], up2(a));
    s = pkfma(wgt2[1], up2(b), s);
    s = pkfma(wgt2[2], up2(c), s);
    s = pkfma(wgt2[3], up2(d), s);
    return cvt_pk_bf16(s.x, s.y);
  };

  auto blendA = [&]() {
    uint4 r;
    r.x = blendW(pf[0].x, pf[1].x, pf[2].x, pf[3].x);
    r.y = blendW(pf[0].y, pf[1].y, pf[2].y, pf[3].y);
    r.z = blendW(pf[0].z, pf[1].z, pf[2].z, pf[3].z);
    r.w = blendW(pf[0].w, pf[1].w, pf[2].w, pf[3].w);
    aw = r;
  };

  char* AB = (char*)&Alds[0];
  char* BB = (char*)&Blds[0];

  // ---- prologue: blend(tile0) into aw, gathers(tile1) in flight ----
  prep(0);
  issueA(0);
  blendA();
  issueA(1);

  for (int it = 0; it < NIT; ++it) {
    // ---- phase A: stage A from registers; B via global_load_lds ----
    *(uint4*)(AB + AldsOff) = aw;
    {
      const char* src = wTb + it * 128;
#pragma unroll
      for (int t = 0; t < 4; ++t)
        glds16(src + t * (64 * KTOT * 2), BB + BldsC[t]);
    }
    asm volatile("s_waitcnt vmcnt(0) lgkmcnt(0)" ::: "memory");
    __builtin_amdgcn_s_barrier();
    asm volatile("" ::: "memory");

    // ---- phase B: blend next A tile, issue gathers(it+2), MFMA current ----
    int nx = it + 1;
    if (nx < NIT) {
      blendA();                        // consumes pf (data for tile nx)
      int nn = it + 2;
      if (nn < NIT) {
        if ((nn & 3) == 0) prep(nn >> 2);
        issueA(nn & 3);                // flies through MFMA + next stage
      }
    }

    __builtin_amdgcn_s_setprio(1);
#pragma unroll
    for (int ksi = 0; ksi < 2; ++ksi) {
      int rc = ksi ? rc1 : rc0;
      short8 af[2];
#pragma unroll
      for (int i = 0; i < 2; ++i)
        af[i] = *(const short8*)(AB + (wm + i * 16 + l15) * 128 + rc);
#pragma unroll
      for (int j = 0; j < 4; ++j) {
        short8 bf = *(const short8*)(BB + (wn + j * 16 + l15) * 128 + rc);
#pragma unroll
        for (int i = 0; i < 2; ++i)
          acc[i][j] = __builtin_amdgcn_mfma_f32_16x16x32_bf16(af[i], bf, acc[i][j], 0, 0, 0);
      }
    }
    __builtin_amdgcn_s_setprio(0);

    asm volatile("s_waitcnt lgkmcnt(0)" ::: "memory");
    __builtin_amdgcn_s_barrier();
    asm volatile("" ::: "memory");
  }

  // ---- epilogue: out[n][co][h][w], float4 along w ----
  float* outp = out + (size_t)n * COUT * HW + (size_t)h * WW + mh * 64;
#pragma unroll
  for (int i = 0; i < 2; ++i) {
    int w0 = wm + i * 16 + l4 * 4;
#pragma unroll
    for (int j = 0; j < 4; ++j) {
      int co = wn + j * 16 + l15;
      *(f32x4*)(outp + (size_t)co * HW + w0) = acc[i][j];
    }
  }
}

extern "C" void kernel_launch(void* const* d_in, const int* in_sizes, int n_in,
                              void* d_out, int out_size, void* d_ws, size_t ws_size,
                              hipStream_t stream) {
  const float* x = (const float*)d_in[0];
  const float* obb = (const float*)d_in[1];
  const float* wgt = (const float*)d_in[2];
  const int* stridep = (const int*)d_in[3];
  float* out = (float*)d_out;

  unsigned short* xt = (unsigned short*)d_ws;          // 2*128*128*256 bf16 = 16.8 MB
  unsigned short* wT = xt + (size_t)2 * HH * WW * CIN; // 256*2304 bf16 = 1.2 MB

  prep_inputs<<<dim3(2048 + 1152), 256, 0, stream>>>(x, wgt, xt, wT);
  fused_deform_gemm<<<dim3(512), 512, 0, stream>>>(obb, xt, wT, out, stridep);
}